// Round 1
// baseline (533.114 us; speedup 1.0000x reference)
//
#include <hip/hip_runtime.h>

// UnitGCN: out = relu( BN(agg_A(conv1x1_Wc(x))) + BN(conv1x1_Wd(x)) )
// x: (64,64,128,25) f32, out: (64,128,128,25) f32
#define N_   64
#define CIN  64
#define T_   128
#define V_   25
#define KK   3
#define CO   128
#define JJ   192              // KK*CIN
#define MCNT 204800.0f        // N*T*V per-channel count for BN

// ws layout (float offsets) — total 593536 floats = 2.37 MB
#define OFF_WC2T 0            // [192][128]
#define OFF_BC2  24576        // [128][25]
#define OFF_WDT  27776        // [64][128]
#define OFF_P1   35968        // [4][1024][128]
#define OFF_P2   560256       // [4][64][128]
#define OFF_STAT 593024       // [4][128]

__global__ void k0_prep(const float* __restrict__ A, const float* __restrict__ Wc,
                        const float* __restrict__ bc, const float* __restrict__ Wd,
                        float* __restrict__ ws) {
    int tid = threadIdx.x;
    for (int e = tid; e < JJ * CO; e += 256) {
        int j = e >> 7, c = e & 127;
        int k = j >> 6, ci = j & 63;
        ws[OFF_WC2T + e] = Wc[(k * CO + c) * CIN + ci];
    }
    for (int e = tid; e < CO * V_; e += 256) {
        int c = e / V_, w = e % V_;
        float s = 0.f;
        for (int k = 0; k < KK; ++k) {
            float b = bc[k * CO + c];
            for (int v = 0; v < V_; ++v) s += b * A[(k * V_ + v) * V_ + w];
        }
        ws[OFF_BC2 + e] = s;
    }
    for (int e = tid; e < CIN * CO; e += 256) {
        int ci = e >> 7, o = e & 127;
        ws[OFF_WDT + e] = Wd[o * CIN + ci];
    }
}

// grid 1024 = (n, t-chunk of 8); block 256 = (s in {0,1}) x (c in [0,128))
__global__ __launch_bounds__(256, 2) void k1_main(
        const float* __restrict__ x, const float* __restrict__ A,
        const float* __restrict__ bd, float* ws, float* __restrict__ y2out) {
    __shared__ float sm[16236];
    float* sA  = sm;          // 1875 used, padded to 1900
    float* sX  = sm + 1900;   // [2][64][28]
    float* sXa = sm + 5484;   // [2][192][28]

    int tid = threadIdx.x;
    int blk = blockIdx.x;
    int n  = blk >> 4;
    int t0 = (blk & 15) << 3;

    for (int e = tid; e < 1875; e += 256) sA[e] = A[e];

    int s = tid >> 7;
    int c = tid & 127;
    const float* wrow = ws + OFF_WC2T + c;
    const float* drow = ws + OFF_WDT + c;
    const float* bb   = ws + OFF_BC2 + c * 25;
    float bdc = bd[c];

    float ys = 0.f, yss = 0.f, rs = 0.f, rss = 0.f;
    float acc[25];

    for (int it = 0; it < 4; ++it) {
        int tp = t0 + it * 2;
        __syncthreads();
        for (int e = tid; e < 3200; e += 256) {
            int ss = e / 1600, r = e % 1600, ci = r / 25, v = r % 25;
            sX[ss * 1792 + ci * 28 + v] = x[((n * CIN + ci) * T_ + tp + ss) * V_ + v];
        }
        __syncthreads();
        for (int e = tid; e < 9600; e += 256) {
            int ss = e / 4800, r = e % 4800, j = r / 25, w = r % 25;
            int k = j >> 6, ci = j & 63;
            const float* xr = &sX[ss * 1792 + ci * 28];
            const float* ar = &sA[k * 625 + w];
            float a = 0.f;
            #pragma unroll
            for (int v = 0; v < 25; ++v) a += xr[v] * ar[v * 25];
            sXa[ss * 5376 + j * 28 + w] = a;
        }
        __syncthreads();
        {   // y2[c][w] = bc2[c][w] + sum_j WcT[j][c] * xa[j][w]
            #pragma unroll
            for (int w = 0; w < 25; ++w) acc[w] = bb[w];
            const float4* xa4 = (const float4*)(&sXa[s * 5376]);
            for (int j = 0; j < JJ; ++j) {
                float wj = wrow[j * CO];
                const float4* q = xa4 + j * 7;
                #pragma unroll
                for (int w4 = 0; w4 < 6; ++w4) {
                    float4 v4 = q[w4];
                    acc[w4 * 4 + 0] += wj * v4.x;
                    acc[w4 * 4 + 1] += wj * v4.y;
                    acc[w4 * 4 + 2] += wj * v4.z;
                    acc[w4 * 4 + 3] += wj * v4.w;
                }
                acc[24] += wj * ((const float*)xa4)[j * 28 + 24];
            }
            int t = tp + s;
            float* yo = y2out + ((n * CO + c) * T_ + t) * V_;
            #pragma unroll
            for (int w = 0; w < 25; ++w) {
                yo[w] = acc[w];
                ys  += acc[w];
                yss += acc[w] * acc[w];
            }
        }
        {   // residual for stats only
            #pragma unroll
            for (int w = 0; w < 25; ++w) acc[w] = bdc;
            const float4* xs4 = (const float4*)(&sX[s * 1792]);
            for (int j = 0; j < CIN; ++j) {
                float wj = drow[j * CO];
                const float4* q = xs4 + j * 7;
                #pragma unroll
                for (int w4 = 0; w4 < 6; ++w4) {
                    float4 v4 = q[w4];
                    acc[w4 * 4 + 0] += wj * v4.x;
                    acc[w4 * 4 + 1] += wj * v4.y;
                    acc[w4 * 4 + 2] += wj * v4.z;
                    acc[w4 * 4 + 3] += wj * v4.w;
                }
                acc[24] += wj * ((const float*)xs4)[j * 28 + 24];
            }
            #pragma unroll
            for (int w = 0; w < 25; ++w) { rs += acc[w]; rss += acc[w] * acc[w]; }
        }
    }
    __syncthreads();
    float* red = sXa;
    red[tid] = ys;  __syncthreads();
    if (tid < 128) ws[OFF_P1 + 0 * 131072 + blk * 128 + tid] = red[tid] + red[tid + 128];
    __syncthreads();
    red[tid] = yss; __syncthreads();
    if (tid < 128) ws[OFF_P1 + 1 * 131072 + blk * 128 + tid] = red[tid] + red[tid + 128];
    __syncthreads();
    red[tid] = rs;  __syncthreads();
    if (tid < 128) ws[OFF_P1 + 2 * 131072 + blk * 128 + tid] = red[tid] + red[tid + 128];
    __syncthreads();
    red[tid] = rss; __syncthreads();
    if (tid < 128) ws[OFF_P1 + 3 * 131072 + blk * 128 + tid] = red[tid] + red[tid + 128];
}

__global__ void k2a(float* ws) {
    int b = blockIdx.x;
    int g = b & 3, ch = b >> 2;
    int c = threadIdx.x;
    const float* p = ws + OFF_P1 + g * 131072 + (ch * 16) * 128 + c;
    float s = 0.f;
    for (int i = 0; i < 16; ++i) s += p[i * 128];
    ws[OFF_P2 + (g * 64 + ch) * 128 + c] = s;
}

__global__ void k2b(const float* __restrict__ gamma, const float* __restrict__ beta,
                    const float* __restrict__ gamma_d, const float* __restrict__ beta_d,
                    float* ws) {
    int tid = threadIdx.x;
    int c = tid & 127;
    int gbase = (tid < 128) ? 0 : 2;
    const float* p = ws + OFF_P2 + gbase * 8192 + c;
    float s1 = 0.f, s2 = 0.f;
    for (int ch = 0; ch < 64; ++ch) { s1 += p[ch * 128]; s2 += p[8192 + ch * 128]; }
    float mean = s1 / MCNT;
    float var  = fmaxf(s2 / MCNT - mean * mean, 0.f);
    float inv  = rsqrtf(var + 1e-5f);
    float ga = (tid < 128) ? gamma[c] : gamma_d[c];
    float be = (tid < 128) ? beta[c]  : beta_d[c];
    float scale = inv * ga;
    float shift = be - mean * scale;
    ws[OFF_STAT + gbase * 128 + c]       = scale;
    ws[OFF_STAT + (gbase + 1) * 128 + c] = shift;
}

// grid 1024 = (n, t-chunk of 8); block 256 = (cl in [0,32)) x (dt in [0,8))
__global__ __launch_bounds__(256, 2) void k3_final(
        const float* __restrict__ x, const float* __restrict__ bd,
        const float* ws, float* out) {
    __shared__ float sX3[14336];   // [cin][dt*28+w], row stride 224
    int tid = threadIdx.x, blk = blockIdx.x;
    int n = blk >> 4, t0 = (blk & 15) << 3;
    for (int e = tid; e < 12800; e += 256) {
        int ci = e / 200, r = e % 200, dt = r / 25, v = r % 25;
        sX3[ci * 224 + dt * 28 + v] = x[((n * CIN + ci) * T_ + t0 + dt) * V_ + v];
    }
    __syncthreads();
    int dt = tid & 7, cl = tid >> 3;
    float racc[25];
    for (int cp = 0; cp < 4; ++cp) {
        int c = cp * 32 + cl;
        float bdc = bd[c];
        #pragma unroll
        for (int w = 0; w < 25; ++w) racc[w] = bdc;
        const float* drow = ws + OFF_WDT + c;
        const float4* xs4 = (const float4*)(&sX3[dt * 28]);
        for (int j = 0; j < CIN; ++j) {
            float wj = drow[j * CO];
            const float4* q = xs4 + j * 56;
            #pragma unroll
            for (int w4 = 0; w4 < 6; ++w4) {
                float4 v4 = q[w4];
                racc[w4 * 4 + 0] += wj * v4.x;
                racc[w4 * 4 + 1] += wj * v4.y;
                racc[w4 * 4 + 2] += wj * v4.z;
                racc[w4 * 4 + 3] += wj * v4.w;
            }
            racc[24] += wj * ((const float*)xs4)[j * 224 + 24];
        }
        float sc  = ws[OFF_STAT + c],       sh  = ws[OFF_STAT + 128 + c];
        float scd = ws[OFF_STAT + 256 + c], shd = ws[OFF_STAT + 384 + c];
        float* g = out + ((n * CO + c) * T_ + t0 + dt) * V_;
        #pragma unroll
        for (int w = 0; w < 25; ++w) {
            float vv = g[w] * sc + sh + racc[w] * scd + shd;
            g[w] = fmaxf(vv, 0.f);
        }
    }
}

extern "C" void kernel_launch(void* const* d_in, const int* in_sizes, int n_in,
                              void* d_out, int out_size, void* d_ws, size_t ws_size,
                              hipStream_t stream) {
    const float* x       = (const float*)d_in[0];
    const float* A       = (const float*)d_in[1];
    const float* Wc      = (const float*)d_in[2];
    const float* bc      = (const float*)d_in[3];
    const float* gamma   = (const float*)d_in[4];
    const float* beta    = (const float*)d_in[5];
    const float* Wd      = (const float*)d_in[6];
    const float* bd      = (const float*)d_in[7];
    const float* gamma_d = (const float*)d_in[8];
    const float* beta_d  = (const float*)d_in[9];
    float* out = (float*)d_out;
    float* ws  = (float*)d_ws;

    k0_prep<<<1, 256, 0, stream>>>(A, Wc, bc, Wd, ws);
    k1_main<<<1024, 256, 0, stream>>>(x, A, bd, ws, out);
    k2a<<<256, 128, 0, stream>>>(ws);
    k2b<<<1, 256, 0, stream>>>(gamma, beta, gamma_d, beta_d, ws);
    k3_final<<<1024, 256, 0, stream>>>(x, bd, ws, out);
}

// Round 3
// 190.202 us; speedup vs baseline: 2.8029x; 2.8029x over previous
//
#include <hip/hip_runtime.h>

typedef __attribute__((ext_vector_type(8))) short short8;
typedef __attribute__((ext_vector_type(4))) float floatx4;

#define N_   64
#define CIN  64
#define T_   128
#define V_   25
#define CO   128
#define MCNT 204800.0f

// ws byte offsets
#define OFF_WCF  0            // ushort[49152]  Wc A-frags [mt8][ks6][lane64][8]
#define OFF_WDF  98304        // ushort[16384]  Wd A-frags [mt8][ks2][lane64][8]
#define OFF_AF   131072       // ushort[3072]   adjacency B-frags [k3][nt2][lane64][8]
#define OFF_BC2  137216       // float[128][32] aggregated bias
#define OFF_P1   153600       // float[4][128][2048] per-block stat partials
#define OFF_SUM  4347904      // float[512]
#define OFF_STAT 4349952      // float[4][128] s1,h1,s2,h2'

__device__ __forceinline__ ushort f2bf(float f) {
    uint u = __float_as_uint(f);
    return (ushort)((u + 0x7FFFu + ((u >> 16) & 1u)) >> 16);  // RNE
}
__device__ __forceinline__ uint pack2(float a, float b) {
    return (uint)f2bf(a) | ((uint)f2bf(b) << 16);
}

// ---------------- k0: weight/adjacency fragment prep ----------------
__global__ void k0_prep(const float* __restrict__ A, const float* __restrict__ Wc,
                        const float* __restrict__ bc, const float* __restrict__ Wd,
                        void* __restrict__ wsv) {
    char* wsb = (char*)wsv;
    ushort* WCF = (ushort*)(wsb + OFF_WCF);
    ushort* WDF = (ushort*)(wsb + OFF_WDF);
    ushort* AFp = (ushort*)(wsb + OFF_AF);
    float*  BC2 = (float*)(wsb + OFF_BC2);
    int tid = threadIdx.x;
    for (int e = tid; e < 49152; e += 256) {
        int fe = e >> 3, el = e & 7;
        int l = fe & 63, q = fe >> 6;
        int mt = q / 6, ks = q % 6;
        int j = ks*32 + (l>>4)*8 + el;      // j = (k,ci) contraction index
        int c = mt*16 + (l & 15);
        int k = j >> 6, ci = j & 63;
        WCF[e] = f2bf(Wc[(k*CO + c)*CIN + ci]);
    }
    for (int e = tid; e < 16384; e += 256) {
        int fe = e >> 3, el = e & 7;
        int l = fe & 63, q = fe >> 6;
        int mt = q >> 1, ks = q & 1;
        int ci = ks*32 + (l>>4)*8 + el;
        int c = mt*16 + (l & 15);
        WDF[e] = f2bf(Wd[c*CIN + ci]);
    }
    for (int e = tid; e < 3072; e += 256) {
        int fe = e >> 3, el = e & 7;
        int l = fe & 63, q = fe >> 6;
        int k = q >> 1, nt = q & 1;
        int w = nt*16 + (l & 15);
        int v = (l>>4)*8 + el;
        AFp[e] = (v < V_ && w < V_) ? f2bf(A[(k*V_ + v)*V_ + w]) : (ushort)0;
    }
    for (int e = tid; e < 4096; e += 256) {
        int c = e >> 5, w = e & 31;
        float s = 0.f;
        if (w < V_) {
            for (int k = 0; k < 3; ++k) {
                float cs = 0.f;
                for (int v = 0; v < V_; ++v) cs += A[(k*V_ + v)*V_ + w];
                s += bc[k*CO + c] * cs;
            }
        }
        BC2[e] = s;
    }
}

// ---------------- k1: MFMA main path + stats ----------------
// grid 2048 = n(64) x tchunk(32, 4 t each); block 512 = 8 waves
__global__ __launch_bounds__(512) void k1_main(
        const float* __restrict__ x, const float* __restrict__ bd,
        void* __restrict__ wsv, float* __restrict__ out) {
    char* wsb = (char*)wsv;
    const ushort* WCF = (const ushort*)(wsb + OFF_WCF);
    const ushort* WDF = (const ushort*)(wsb + OFF_WDF);
    const ushort* AF  = (const ushort*)(wsb + OFF_AF);
    const float*  BC2 = (const float*)(wsb + OFF_BC2);
    float* P1 = (float*)(wsb + OFF_P1);

    __shared__ ushort XR[8192];    // x slab bf16, [ci64][t4][v32], 16B-slot XOR swizzle (2-bit key)
    __shared__ ushort BB[8192];    // B-frag buffer: [ks2][nt8][lane64][8]
    short8* XR8 = (short8*)XR;
    short8* BB8 = (short8*)BB;
    uint*   XRu = (uint*)XR;
    uint*   BBu = (uint*)BB;

    const int tid = threadIdx.x;
    const int l = tid & 63, wv = tid >> 6;
    const int blk = blockIdx.x;
    const int nb = blk >> 5, tcb = blk & 31;
    const long xbase = (long)nb * (CIN * T_ * V_);
    const int tg0 = tcb * 4;

    // ---- stage x -> XR (bf16, zero-padded v>=25, swizzled) ----
    #pragma unroll
    for (int i = 0; i < 8; ++i) {
        int p = tid + i * 512;
        int ci = p >> 6, rem = p & 63, t = rem >> 4, vp = rem & 15, v = vp * 2;
        float f0 = 0.f, f1 = 0.f;
        if (v < V_)     f0 = x[xbase + ci*(T_*V_) + (tg0 + t)*V_ + v];
        if (v + 1 < V_) f1 = x[xbase + ci*(T_*V_) + (tg0 + t)*V_ + v + 1];
        int idx = (ci*4 + t)*16 + 4*((v >> 3) ^ (ci & 3)) + ((v & 7) >> 1);
        XRu[idx] = (uint)f2bf(f0) | ((uint)f2bf(f1) << 16);
    }

    // Wc A-frags for this wave's M-tile (c-block wv)
    short8 wcf[6];
    #pragma unroll
    for (int ks = 0; ks < 6; ++ks)
        wcf[ks] = *(const short8*)(WCF + ((wv*6 + ks)*64 + l)*8);

    __syncthreads();

    // ---- residual: produce x B-frags (K=ci) into BB ----
    #pragma unroll
    for (int i = 0; i < 2; ++i) {
        int task = tid + i*512;
        int fid = task >> 6, tl = task & 63;
        int n = (fid & 7)*16 + (tl & 15), t = n >> 5, v = n & 31;
        short8 r8;
        #pragma unroll
        for (int e = 0; e < 8; ++e) {
            int ci = (fid >> 3)*32 + (tl >> 4)*8 + e;
            r8[e] = (short)XR[(ci*4 + t)*32 + 8*((v >> 3) ^ (ci & 3)) + (v & 7)];
        }
        BB8[fid*64 + tl] = r8;
    }
    __syncthreads();

    // ---- residual MFMA + stats (values discarded, recomputed in k3) ----
    float rs[4] = {0,0,0,0}, rss[4] = {0,0,0,0};
    {
        short8 wdf[2];
        #pragma unroll
        for (int ks = 0; ks < 2; ++ks)
            wdf[ks] = *(const short8*)(WDF + ((wv*2 + ks)*64 + l)*8);
        floatx4 racc[8];
        #pragma unroll
        for (int i = 0; i < 8; ++i) racc[i] = (floatx4){0,0,0,0};
        #pragma unroll
        for (int ks = 0; ks < 2; ++ks)
            #pragma unroll
            for (int ntm = 0; ntm < 8; ++ntm)
                racc[ntm] = __builtin_amdgcn_mfma_f32_16x16x32_bf16(
                    wdf[ks], BB8[(ks*8 + ntm)*64 + l], racc[ntm], 0, 0, 0);
        float bdv[4];
        #pragma unroll
        for (int r = 0; r < 4; ++r) bdv[r] = bd[wv*16 + (l >> 4)*4 + r];
        #pragma unroll
        for (int ntm = 0; ntm < 8; ++ntm) {
            int n = ntm*16 + (l & 15);
            bool valid = (n & 31) < V_;
            #pragma unroll
            for (int r = 0; r < 4; ++r) {
                float val = racc[ntm][r] + bdv[r];
                if (valid) { rs[r] += val; rss[r] += val*val; }
            }
        }
    }
    #pragma unroll
    for (int m = 1; m < 16; m <<= 1)
        #pragma unroll
        for (int r = 0; r < 4; ++r) {
            rs[r]  += __shfl_xor(rs[r],  m);
            rss[r] += __shfl_xor(rss[r], m);
        }
    if ((l & 15) == 0)
        #pragma unroll
        for (int r = 0; r < 4; ++r) {
            int c = wv*16 + (l >> 4)*4 + r;
            P1[(2*128 + c)*2048 + blk] = rs[r];
            P1[(3*128 + c)*2048 + blk] = rss[r];
        }

    // ---- main path: agg (MFMA) -> y2 GEMM (MFMA) ----
    const int t_a = wv & 3, nt_a = wv >> 2;     // this wave's agg assignment
    short8 xf[4];                                // x A-frags (M=ci), t = t_a
    #pragma unroll
    for (int mt = 0; mt < 4; ++mt) {
        int ci = mt*16 + (l & 15), vg = l >> 4;
        xf[mt] = XR8[(ci*4 + t_a)*4 + (vg ^ (ci & 3))];
    }
    floatx4 acc[8];
    #pragma unroll
    for (int i = 0; i < 8; ++i) acc[i] = (floatx4){0,0,0,0};

    for (int k = 0; k < 3; ++k) {
        __syncthreads();   // BB reads of previous phase done
        short8 am = *(const short8*)(AF + ((k*2 + nt_a)*64 + l)*8);
        int ntm_a = t_a*2 + nt_a;
        #pragma unroll
        for (int mt = 0; mt < 4; ++mt) {
            floatx4 agc = __builtin_amdgcn_mfma_f32_16x16x32_bf16(
                xf[mt], am, (floatx4){0,0,0,0}, 0, 0, 0);
            int kb = mt >> 1;
            #pragma unroll
            for (int rp = 0; rp < 4; rp += 2) {
                int jo = (l >> 4)*4 + rp;
                int lf = (l & 15) + 16*((mt & 1)*2 + (jo >> 3));
                int ef = jo & 7;
                BBu[(((kb*8 + ntm_a)*64 + lf)*16 + ef*2) >> 2] = pack2(agc[rp], agc[rp+1]);
            }
        }
        __syncthreads();   // BB writes visible
        #pragma unroll
        for (int kb = 0; kb < 2; ++kb)
            #pragma unroll
            for (int ntm = 0; ntm < 8; ++ntm)
                acc[ntm] = __builtin_amdgcn_mfma_f32_16x16x32_bf16(
                    wcf[k*2 + kb], BB8[(kb*8 + ntm)*64 + l], acc[ntm], 0, 0, 0);
    }

    // ---- epilogue: bias, store y2 (pre-BN), stats ----
    float ys[4] = {0,0,0,0}, yss[4] = {0,0,0,0};
    const int cbase = wv*16 + (l >> 4)*4;
    #pragma unroll
    for (int ntm = 0; ntm < 8; ++ntm) {
        int n = ntm*16 + (l & 15), t = n >> 5, w = n & 31;
        bool valid = w < V_;
        int tg = tg0 + t;
        #pragma unroll
        for (int r = 0; r < 4; ++r) {
            int c = cbase + r;
            float val = acc[ntm][r] + BC2[c*32 + w];
            if (valid) {
                out[(((long)nb*CO + c)*T_ + tg)*V_ + w] = val;
                ys[r] += val; yss[r] += val*val;
            }
        }
    }
    #pragma unroll
    for (int m = 1; m < 16; m <<= 1)
        #pragma unroll
        for (int r = 0; r < 4; ++r) {
            ys[r]  += __shfl_xor(ys[r],  m);
            yss[r] += __shfl_xor(yss[r], m);
        }
    if ((l & 15) == 0)
        #pragma unroll
        for (int r = 0; r < 4; ++r) {
            int c = cbase + r;
            P1[(0*128 + c)*2048 + blk] = ys[r];
            P1[(1*128 + c)*2048 + blk] = yss[r];
        }
}

// ---------------- k2a/k2b: deterministic stat reduction ----------------
__global__ void k2a(void* __restrict__ wsv) {
    char* wsb = (char*)wsv;
    const float* P1 = (const float*)(wsb + OFF_P1);
    float* SUM = (float*)(wsb + OFF_SUM);
    __shared__ float red[256];
    int gc = blockIdx.x;
    float s = 0.f;
    for (int i = threadIdx.x; i < 2048; i += 256) s += P1[(long)gc*2048 + i];
    red[threadIdx.x] = s; __syncthreads();
    for (int st = 128; st > 0; st >>= 1) {
        if (threadIdx.x < st) red[threadIdx.x] += red[threadIdx.x + st];
        __syncthreads();
    }
    if (threadIdx.x == 0) SUM[gc] = red[0];
}

__global__ void k2b(const float* __restrict__ gamma, const float* __restrict__ beta,
                    const float* __restrict__ gamma_d, const float* __restrict__ beta_d,
                    const float* __restrict__ bd, void* __restrict__ wsv) {
    char* wsb = (char*)wsv;
    const float* SUM = (const float*)(wsb + OFF_SUM);
    float* STAT = (float*)(wsb + OFF_STAT);
    int c = threadIdx.x;
    if (c < 128) {
        float my = SUM[c] / MCNT;
        float vy = fmaxf(SUM[128 + c] / MCNT - my*my, 0.f);
        float s1 = rsqrtf(vy + 1e-5f) * gamma[c];
        float h1 = beta[c] - my * s1;
        float mr = SUM[256 + c] / MCNT;
        float vr = fmaxf(SUM[384 + c] / MCNT - mr*mr, 0.f);
        float s2 = rsqrtf(vr + 1e-5f) * gamma_d[c];
        float h2 = beta_d[c] - mr * s2 + bd[c] * s2;   // fold bd: k3 recomputes conv only
        STAT[c] = s1; STAT[128 + c] = h1; STAT[256 + c] = s2; STAT[384 + c] = h2;
    }
}

// ---------------- k3: recompute residual (MFMA), combine, ReLU ----------------
__global__ __launch_bounds__(512) void k3_final(
        const float* __restrict__ x, void* __restrict__ wsv, float* __restrict__ out) {
    char* wsb = (char*)wsv;
    const ushort* WDF = (const ushort*)(wsb + OFF_WDF);
    const float* STAT = (const float*)(wsb + OFF_STAT);

    __shared__ ushort XR[8192];
    __shared__ ushort BB[8192];
    short8* BB8 = (short8*)BB;
    uint*   XRu = (uint*)XR;

    const int tid = threadIdx.x;
    const int l = tid & 63, wv = tid >> 6;
    const int blk = blockIdx.x;
    const int nb = blk >> 5, tcb = blk & 31;
    const long xbase = (long)nb * (CIN * T_ * V_);
    const int tg0 = tcb * 4;

    #pragma unroll
    for (int i = 0; i < 8; ++i) {
        int p = tid + i * 512;
        int ci = p >> 6, rem = p & 63, t = rem >> 4, vp = rem & 15, v = vp * 2;
        float f0 = 0.f, f1 = 0.f;
        if (v < V_)     f0 = x[xbase + ci*(T_*V_) + (tg0 + t)*V_ + v];
        if (v + 1 < V_) f1 = x[xbase + ci*(T_*V_) + (tg0 + t)*V_ + v + 1];
        int idx = (ci*4 + t)*16 + 4*((v >> 3) ^ (ci & 3)) + ((v & 7) >> 1);
        XRu[idx] = (uint)f2bf(f0) | ((uint)f2bf(f1) << 16);
    }
    __syncthreads();

    #pragma unroll
    for (int i = 0; i < 2; ++i) {
        int task = tid + i*512;
        int fid = task >> 6, tl = task & 63;
        int n = (fid & 7)*16 + (tl & 15), t = n >> 5, v = n & 31;
        short8 r8;
        #pragma unroll
        for (int e = 0; e < 8; ++e) {
            int ci = (fid >> 3)*32 + (tl >> 4)*8 + e;
            r8[e] = (short)XR[(ci*4 + t)*32 + 8*((v >> 3) ^ (ci & 3)) + (v & 7)];
        }
        BB8[fid*64 + tl] = r8;
    }
    __syncthreads();

    short8 wdf[2];
    #pragma unroll
    for (int ks = 0; ks < 2; ++ks)
        wdf[ks] = *(const short8*)(WDF + ((wv*2 + ks)*64 + l)*8);
    floatx4 racc[8];
    #pragma unroll
    for (int i = 0; i < 8; ++i) racc[i] = (floatx4){0,0,0,0};
    #pragma unroll
    for (int ks = 0; ks < 2; ++ks)
        #pragma unroll
        for (int ntm = 0; ntm < 8; ++ntm)
            racc[ntm] = __builtin_amdgcn_mfma_f32_16x16x32_bf16(
                wdf[ks], BB8[(ks*8 + ntm)*64 + l], racc[ntm], 0, 0, 0);

    const int cbase = wv*16 + (l >> 4)*4;
    float s1[4], h1[4], s2[4], h2[4];
    #pragma unroll
    for (int r = 0; r < 4; ++r) {
        int c = cbase + r;
        s1[r] = STAT[c]; h1[r] = STAT[128 + c];
        s2[r] = STAT[256 + c]; h2[r] = STAT[384 + c];
    }
    #pragma unroll
    for (int ntm = 0; ntm < 8; ++ntm) {
        int n = ntm*16 + (l & 15), t = n >> 5, w = n & 31;
        if (w < V_) {
            int tg = tg0 + t;
            #pragma unroll
            for (int r = 0; r < 4; ++r) {
                int c = cbase + r;
                long a = (((long)nb*CO + c)*T_ + tg)*V_ + w;
                float o = out[a]*s1[r] + h1[r] + racc[ntm][r]*s2[r] + h2[r];
                out[a] = fmaxf(o, 0.f);
            }
        }
    }
}

extern "C" void kernel_launch(void* const* d_in, const int* in_sizes, int n_in,
                              void* d_out, int out_size, void* d_ws, size_t ws_size,
                              hipStream_t stream) {
    const float* x       = (const float*)d_in[0];
    const float* A       = (const float*)d_in[1];
    const float* Wc      = (const float*)d_in[2];
    const float* bc      = (const float*)d_in[3];
    const float* gamma   = (const float*)d_in[4];
    const float* beta    = (const float*)d_in[5];
    const float* Wd      = (const float*)d_in[6];
    const float* bd      = (const float*)d_in[7];
    const float* gamma_d = (const float*)d_in[8];
    const float* beta_d  = (const float*)d_in[9];
    float* out = (float*)d_out;

    k0_prep<<<1, 256, 0, stream>>>(A, Wc, bc, Wd, d_ws);
    k1_main<<<2048, 512, 0, stream>>>(x, bd, d_ws, out);
    k2a<<<512, 256, 0, stream>>>(d_ws);
    k2b<<<1, 128, 0, stream>>>(gamma, beta, gamma_d, beta_d, bd, d_ws);
    k3_final<<<2048, 512, 0, stream>>>(x, d_ws, out);
}

// Round 4
// 174.780 us; speedup vs baseline: 3.0502x; 1.0882x over previous
//
#include <hip/hip_runtime.h>

typedef __attribute__((ext_vector_type(8))) short short8;
typedef __attribute__((ext_vector_type(4))) float floatx4;

#define N_   64
#define CIN  64
#define T_   128
#define V_   25
#define CO   128
#define MCNT 204800.0f

// ws byte offsets
#define OFF_WCF  0            // ushort[49152]  Wc A-frags [mt8][ks6][lane64][8]
#define OFF_WDF  98304        // ushort[16384]  Wd A-frags [mt8][ks2][lane64][8]
#define OFF_WDF2 131072       // ushort[16384]  Wd frags scaled by s2/s1
#define OFF_AF   163840       // ushort[3072]   adjacency B-frags [k3][nt2][lane64][8]
#define OFF_BC2  169984       // float[128][32] aggregated bias
#define OFF_HH   186368       // float[128][32] folded affine shift
#define OFF_P1   202752       // float[4][128][2048] per-block stat partials
#define OFF_SUM  4397056      // float[512]
#define OFF_STAT 4399104      // float[128] s1

__device__ __forceinline__ ushort f2bf(float f) {
    uint u = __float_as_uint(f);
    return (ushort)((u + 0x7FFFu + ((u >> 16) & 1u)) >> 16);  // RNE
}
__device__ __forceinline__ uint pack2(float a, float b) {
    return (uint)f2bf(a) | ((uint)f2bf(b) << 16);
}

// ---------------- k0: weight/adjacency fragment prep ----------------
__global__ void k0_prep(const float* __restrict__ A, const float* __restrict__ Wc,
                        const float* __restrict__ bc, const float* __restrict__ Wd,
                        void* __restrict__ wsv) {
    char* wsb = (char*)wsv;
    ushort* WCF = (ushort*)(wsb + OFF_WCF);
    ushort* WDF = (ushort*)(wsb + OFF_WDF);
    ushort* AFp = (ushort*)(wsb + OFF_AF);
    float*  BC2 = (float*)(wsb + OFF_BC2);
    int tid = threadIdx.x;
    for (int e = tid; e < 49152; e += 256) {
        int fe = e >> 3, el = e & 7;
        int l = fe & 63, q = fe >> 6;
        int mt = q / 6, ks = q % 6;
        int j = ks*32 + (l>>4)*8 + el;      // j = (k,ci) contraction index
        int c = mt*16 + (l & 15);
        int k = j >> 6, ci = j & 63;
        WCF[e] = f2bf(Wc[(k*CO + c)*CIN + ci]);
    }
    for (int e = tid; e < 16384; e += 256) {
        int fe = e >> 3, el = e & 7;
        int l = fe & 63, q = fe >> 6;
        int mt = q >> 1, ks = q & 1;
        int ci = ks*32 + (l>>4)*8 + el;
        int c = mt*16 + (l & 15);
        WDF[e] = f2bf(Wd[c*CIN + ci]);
    }
    for (int e = tid; e < 3072; e += 256) {
        int fe = e >> 3, el = e & 7;
        int l = fe & 63, q = fe >> 6;
        int k = q >> 1, nt = q & 1;
        int w = nt*16 + (l & 15);
        int v = (l>>4)*8 + el;
        AFp[e] = (v < V_ && w < V_) ? f2bf(A[(k*V_ + v)*V_ + w]) : (ushort)0;
    }
    for (int e = tid; e < 4096; e += 256) {
        int c = e >> 5, w = e & 31;
        float s = 0.f;
        if (w < V_) {
            for (int k = 0; k < 3; ++k) {
                float cs = 0.f;
                for (int v = 0; v < V_; ++v) cs += A[(k*V_ + v)*V_ + w];
                s += bc[k*CO + c] * cs;
            }
        }
        BC2[e] = s;
    }
}

// ---------------- k1: MFMA forward, stats only (nothing big stored) ----------------
// grid 2048; decode nb = blk&63 (XCD affinity), tcb = blk>>6; block 512 = 8 waves
__global__ __launch_bounds__(512) void k1_main(
        const float* __restrict__ x, const float* __restrict__ bd,
        void* __restrict__ wsv) {
    char* wsb = (char*)wsv;
    const ushort* WCF = (const ushort*)(wsb + OFF_WCF);
    const ushort* WDF = (const ushort*)(wsb + OFF_WDF);
    const ushort* AF  = (const ushort*)(wsb + OFF_AF);
    const float*  BC2 = (const float*)(wsb + OFF_BC2);
    float* P1 = (float*)(wsb + OFF_P1);

    __shared__ ushort XR[8192];    // [ci64][t4][v32] bf16, 16B-slot XOR swizzle (2-bit key)
    __shared__ ushort BB[8192];    // B-frag buffer: [ks2][nt8][lane64][8]
    short8* XR8 = (short8*)XR;
    short8* BB8 = (short8*)BB;
    uint*   XRu = (uint*)XR;
    uint*   BBu = (uint*)BB;

    const int tid = threadIdx.x;
    const int l = tid & 63, wv = tid >> 6;
    const int blk = blockIdx.x;
    const int nb = blk & 63, tcb = blk >> 6;
    const long xbase = (long)nb * (CIN * T_ * V_);
    const int tg0 = tcb * 4;

    #pragma unroll
    for (int i = 0; i < 8; ++i) {
        int p = tid + i * 512;
        int ci = p >> 6, rem = p & 63, t = rem >> 4, vp = rem & 15, v = vp * 2;
        float f0 = 0.f, f1 = 0.f;
        if (v < V_)     f0 = x[xbase + ci*(T_*V_) + (tg0 + t)*V_ + v];
        if (v + 1 < V_) f1 = x[xbase + ci*(T_*V_) + (tg0 + t)*V_ + v + 1];
        int idx = (ci*4 + t)*16 + 4*((v >> 3) ^ (ci & 3)) + ((v & 7) >> 1);
        XRu[idx] = (uint)f2bf(f0) | ((uint)f2bf(f1) << 16);
    }

    short8 wcf[6];
    #pragma unroll
    for (int ks = 0; ks < 6; ++ks)
        wcf[ks] = *(const short8*)(WCF + ((wv*6 + ks)*64 + l)*8);

    __syncthreads();

    // residual B-frags (K=ci)
    #pragma unroll
    for (int i = 0; i < 2; ++i) {
        int task = tid + i*512;
        int fid = task >> 6, tl = task & 63;
        int n = (fid & 7)*16 + (tl & 15), t = n >> 5, v = n & 31;
        short8 r8;
        #pragma unroll
        for (int e = 0; e < 8; ++e) {
            int ci = (fid >> 3)*32 + (tl >> 4)*8 + e;
            r8[e] = (short)XR[(ci*4 + t)*32 + 8*((v >> 3) ^ (ci & 3)) + (v & 7)];
        }
        BB8[fid*64 + tl] = r8;
    }
    __syncthreads();

    // residual MFMA -> stats
    float rs[4] = {0,0,0,0}, rss[4] = {0,0,0,0};
    {
        short8 wdf[2];
        #pragma unroll
        for (int ks = 0; ks < 2; ++ks)
            wdf[ks] = *(const short8*)(WDF + ((wv*2 + ks)*64 + l)*8);
        floatx4 racc[8];
        #pragma unroll
        for (int i = 0; i < 8; ++i) racc[i] = (floatx4){0,0,0,0};
        #pragma unroll
        for (int ks = 0; ks < 2; ++ks)
            #pragma unroll
            for (int ntm = 0; ntm < 8; ++ntm)
                racc[ntm] = __builtin_amdgcn_mfma_f32_16x16x32_bf16(
                    wdf[ks], BB8[(ks*8 + ntm)*64 + l], racc[ntm], 0, 0, 0);
        float bdv[4];
        #pragma unroll
        for (int r = 0; r < 4; ++r) bdv[r] = bd[wv*16 + (l >> 4)*4 + r];
        #pragma unroll
        for (int ntm = 0; ntm < 8; ++ntm) {
            int n = ntm*16 + (l & 15);
            bool valid = (n & 31) < V_;
            #pragma unroll
            for (int r = 0; r < 4; ++r) {
                float val = racc[ntm][r] + bdv[r];
                if (valid) { rs[r] += val; rss[r] += val*val; }
            }
        }
    }
    #pragma unroll
    for (int m = 1; m < 16; m <<= 1)
        #pragma unroll
        for (int r = 0; r < 4; ++r) {
            rs[r]  += __shfl_xor(rs[r],  m);
            rss[r] += __shfl_xor(rss[r], m);
        }
    if ((l & 15) == 0)
        #pragma unroll
        for (int r = 0; r < 4; ++r) {
            int c = wv*16 + (l >> 4)*4 + r;
            P1[(2*128 + c)*2048 + blk] = rs[r];
            P1[(3*128 + c)*2048 + blk] = rss[r];
        }

    // main path: agg (MFMA) -> y2 GEMM (MFMA)
    const int t_a = wv & 3, nt_a = wv >> 2;
    short8 xf[4];
    #pragma unroll
    for (int mt = 0; mt < 4; ++mt) {
        int ci = mt*16 + (l & 15), vg = l >> 4;
        xf[mt] = XR8[(ci*4 + t_a)*4 + (vg ^ (ci & 3))];
    }
    floatx4 acc[8];
    #pragma unroll
    for (int i = 0; i < 8; ++i) acc[i] = (floatx4){0,0,0,0};

    for (int k = 0; k < 3; ++k) {
        __syncthreads();
        short8 am = *(const short8*)(AF + ((k*2 + nt_a)*64 + l)*8);
        int ntm_a = t_a*2 + nt_a;
        #pragma unroll
        for (int mt = 0; mt < 4; ++mt) {
            floatx4 agc = __builtin_amdgcn_mfma_f32_16x16x32_bf16(
                xf[mt], am, (floatx4){0,0,0,0}, 0, 0, 0);
            int kb = mt >> 1;
            #pragma unroll
            for (int rp = 0; rp < 4; rp += 2) {
                int jo = (l >> 4)*4 + rp;
                int lf = (l & 15) + 16*((mt & 1)*2 + (jo >> 3));
                int ef = jo & 7;
                BBu[(((kb*8 + ntm_a)*64 + lf)*16 + ef*2) >> 2] = pack2(agc[rp], agc[rp+1]);
            }
        }
        __syncthreads();
        #pragma unroll
        for (int kb = 0; kb < 2; ++kb)
            #pragma unroll
            for (int ntm = 0; ntm < 8; ++ntm)
                acc[ntm] = __builtin_amdgcn_mfma_f32_16x16x32_bf16(
                    wcf[k*2 + kb], BB8[(kb*8 + ntm)*64 + l], acc[ntm], 0, 0, 0);
    }

    // stats only
    float ys[4] = {0,0,0,0}, yss[4] = {0,0,0,0};
    const int cbase = wv*16 + (l >> 4)*4;
    #pragma unroll
    for (int ntm = 0; ntm < 8; ++ntm) {
        int n = ntm*16 + (l & 15), w = n & 31;
        bool valid = w < V_;
        #pragma unroll
        for (int r = 0; r < 4; ++r) {
            int c = cbase + r;
            float val = acc[ntm][r] + BC2[c*32 + w];
            if (valid) { ys[r] += val; yss[r] += val*val; }
        }
    }
    #pragma unroll
    for (int m = 1; m < 16; m <<= 1)
        #pragma unroll
        for (int r = 0; r < 4; ++r) {
            ys[r]  += __shfl_xor(ys[r],  m);
            yss[r] += __shfl_xor(yss[r], m);
        }
    if ((l & 15) == 0)
        #pragma unroll
        for (int r = 0; r < 4; ++r) {
            int c = cbase + r;
            P1[(0*128 + c)*2048 + blk] = ys[r];
            P1[(1*128 + c)*2048 + blk] = yss[r];
        }
}

// ---------------- k2a/k2b: deterministic stat reduction + folding ----------------
__global__ void k2a(void* __restrict__ wsv) {
    char* wsb = (char*)wsv;
    const float* P1 = (const float*)(wsb + OFF_P1);
    float* SUM = (float*)(wsb + OFF_SUM);
    __shared__ float red[256];
    int gc = blockIdx.x;
    float s = 0.f;
    for (int i = threadIdx.x; i < 2048; i += 256) s += P1[(long)gc*2048 + i];
    red[threadIdx.x] = s; __syncthreads();
    for (int st = 128; st > 0; st >>= 1) {
        if (threadIdx.x < st) red[threadIdx.x] += red[threadIdx.x + st];
        __syncthreads();
    }
    if (threadIdx.x == 0) SUM[gc] = red[0];
}

__global__ void k2b(const float* __restrict__ gamma, const float* __restrict__ beta,
                    const float* __restrict__ gamma_d, const float* __restrict__ beta_d,
                    const float* __restrict__ bd, void* __restrict__ wsv) {
    char* wsb = (char*)wsv;
    const float* SUM = (const float*)(wsb + OFF_SUM);
    const float* BC2 = (const float*)(wsb + OFF_BC2);
    const ushort* WDF = (const ushort*)(wsb + OFF_WDF);
    ushort* WDF2 = (ushort*)(wsb + OFF_WDF2);
    float* HH   = (float*)(wsb + OFF_HH);
    float* STAT = (float*)(wsb + OFF_STAT);
    __shared__ float s1s[128], rrs[128], hs[128];
    int tid = threadIdx.x;
    if (tid < 128) {
        int c = tid;
        float my = SUM[c] / MCNT;
        float vy = fmaxf(SUM[128 + c] / MCNT - my*my, 0.f);
        float s1 = rsqrtf(vy + 1e-5f) * gamma[c];
        float h1 = beta[c] - my * s1;
        float mr = SUM[256 + c] / MCNT;
        float vr = fmaxf(SUM[384 + c] / MCNT - mr*mr, 0.f);
        float s2 = rsqrtf(vr + 1e-5f) * gamma_d[c];
        float h2 = beta_d[c] - mr * s2 + bd[c] * s2;
        STAT[c] = s1;
        s1s[c] = s1;
        float d = (fabsf(s1) > 1e-20f) ? s1 : 1e-20f;
        rrs[c] = s2 / d;
        hs[c]  = h1 + h2;
    }
    __syncthreads();
    for (int e = tid; e < 4096; e += 256) {
        int c = e >> 5;
        HH[e] = BC2[e] * s1s[c] + hs[c];
    }
    for (int e = tid; e < 16384; e += 256) {
        int fe = e >> 3, l = fe & 63, q = fe >> 6, mt = q >> 1;
        int c = mt*16 + (l & 15);
        float wv = __uint_as_float(((uint)WDF[e]) << 16);
        WDF2[e] = f2bf(wv * rrs[c]);
    }
}

// ---------------- k3: recompute forward, fold BNs, ReLU, coalesced store ----------------
__global__ __launch_bounds__(512) void k3_final(
        const float* __restrict__ x, void* __restrict__ wsv, float* __restrict__ out) {
    char* wsb = (char*)wsv;
    const ushort* WCF  = (const ushort*)(wsb + OFF_WCF);
    const ushort* WDF2 = (const ushort*)(wsb + OFF_WDF2);
    const ushort* AF   = (const ushort*)(wsb + OFF_AF);
    const float*  HH   = (const float*)(wsb + OFF_HH);
    const float*  STAT = (const float*)(wsb + OFF_STAT);

    __shared__ uint SM[12800];              // 51200 B union
    ushort* XR  = (ushort*)SM;              // 16 KB
    uint*   XRu = SM;
    short8* XR8 = (short8*)SM;
    uint*   BBu = SM + 4096;                // 16 KB at byte 16384
    short8* BB8 = (short8*)BBu;
    float*  OST = (float*)SM;               // 51.2 KB (reused after compute)

    const int tid = threadIdx.x;
    const int l = tid & 63, wv = tid >> 6;
    const int blk = blockIdx.x;
    const int nb = blk & 63, tcb = blk >> 6;
    const long xbase = (long)nb * (CIN * T_ * V_);
    const int tg0 = tcb * 4;

    #pragma unroll
    for (int i = 0; i < 8; ++i) {
        int p = tid + i * 512;
        int ci = p >> 6, rem = p & 63, t = rem >> 4, vp = rem & 15, v = vp * 2;
        float f0 = 0.f, f1 = 0.f;
        if (v < V_)     f0 = x[xbase + ci*(T_*V_) + (tg0 + t)*V_ + v];
        if (v + 1 < V_) f1 = x[xbase + ci*(T_*V_) + (tg0 + t)*V_ + v + 1];
        int idx = (ci*4 + t)*16 + 4*((v >> 3) ^ (ci & 3)) + ((v & 7) >> 1);
        XRu[idx] = (uint)f2bf(f0) | ((uint)f2bf(f1) << 16);
    }

    short8 wcf[6];
    #pragma unroll
    for (int ks = 0; ks < 6; ++ks)
        wcf[ks] = *(const short8*)(WCF + ((wv*6 + ks)*64 + l)*8);

    __syncthreads();

    // residual B-frags
    #pragma unroll
    for (int i = 0; i < 2; ++i) {
        int task = tid + i*512;
        int fid = task >> 6, tl = task & 63;
        int n = (fid & 7)*16 + (tl & 15), t = n >> 5, v = n & 31;
        short8 r8;
        #pragma unroll
        for (int e = 0; e < 8; ++e) {
            int ci = (fid >> 3)*32 + (tl >> 4)*8 + e;
            r8[e] = (short)XR[(ci*4 + t)*32 + 8*((v >> 3) ^ (ci & 3)) + (v & 7)];
        }
        BB8[fid*64 + tl] = r8;
    }
    __syncthreads();

    // residual MFMA directly into acc (Wd pre-scaled by s2/s1)
    floatx4 acc[8];
    #pragma unroll
    for (int i = 0; i < 8; ++i) acc[i] = (floatx4){0,0,0,0};
    {
        short8 wdf[2];
        #pragma unroll
        for (int ks = 0; ks < 2; ++ks)
            wdf[ks] = *(const short8*)(WDF2 + ((wv*2 + ks)*64 + l)*8);
        #pragma unroll
        for (int ks = 0; ks < 2; ++ks)
            #pragma unroll
            for (int ntm = 0; ntm < 8; ++ntm)
                acc[ntm] = __builtin_amdgcn_mfma_f32_16x16x32_bf16(
                    wdf[ks], BB8[(ks*8 + ntm)*64 + l], acc[ntm], 0, 0, 0);
    }

    const int t_a = wv & 3, nt_a = wv >> 2;
    short8 xf[4];
    #pragma unroll
    for (int mt = 0; mt < 4; ++mt) {
        int ci = mt*16 + (l & 15), vg = l >> 4;
        xf[mt] = XR8[(ci*4 + t_a)*4 + (vg ^ (ci & 3))];
    }

    for (int k = 0; k < 3; ++k) {
        __syncthreads();
        short8 am = *(const short8*)(AF + ((k*2 + nt_a)*64 + l)*8);
        int ntm_a = t_a*2 + nt_a;
        #pragma unroll
        for (int mt = 0; mt < 4; ++mt) {
            floatx4 agc = __builtin_amdgcn_mfma_f32_16x16x32_bf16(
                xf[mt], am, (floatx4){0,0,0,0}, 0, 0, 0);
            int kb = mt >> 1;
            #pragma unroll
            for (int rp = 0; rp < 4; rp += 2) {
                int jo = (l >> 4)*4 + rp;
                int lf = (l & 15) + 16*((mt & 1)*2 + (jo >> 3));
                int ef = jo & 7;
                BBu[(((kb*8 + ntm_a)*64 + lf)*16 + ef*2) >> 2] = pack2(agc[rp], agc[rp+1]);
            }
        }
        __syncthreads();
        #pragma unroll
        for (int kb = 0; kb < 2; ++kb)
            #pragma unroll
            for (int ntm = 0; ntm < 8; ++ntm)
                acc[ntm] = __builtin_amdgcn_mfma_f32_16x16x32_bf16(
                    wcf[k*2 + kb], BB8[(kb*8 + ntm)*64 + l], acc[ntm], 0, 0, 0);
    }

    // epilogue: scale, shift, relu -> LDS staging
    const int cbase = wv*16 + (l >> 4)*4;
    float s1v[4];
    #pragma unroll
    for (int r = 0; r < 4; ++r) s1v[r] = STAT[cbase + r];

    __syncthreads();   // all BB/XR readers done before OST overwrite
    #pragma unroll
    for (int ntm = 0; ntm < 8; ++ntm) {
        int n = ntm*16 + (l & 15), t = n >> 5, w = n & 31;
        if (w < V_) {
            #pragma unroll
            for (int r = 0; r < 4; ++r) {
                int c = cbase + r;
                float val = acc[ntm][r] * s1v[r] + HH[c*32 + w];
                OST[c*100 + t*25 + w] = fmaxf(val, 0.f);
            }
        }
    }
    __syncthreads();

    // coalesced float4 store: per c, 400B contiguous run
    const long ob = (long)nb * 409600 + tcb * 100;
    for (int task = tid; task < 3200; task += 512) {
        int c = task / 25, q = task - c * 25;
        float4 v = *(const float4*)(OST + c*100 + q*4);
        *(float4*)(out + ob + (long)c*3200 + q*4) = v;
    }
}

extern "C" void kernel_launch(void* const* d_in, const int* in_sizes, int n_in,
                              void* d_out, int out_size, void* d_ws, size_t ws_size,
                              hipStream_t stream) {
    const float* x       = (const float*)d_in[0];
    const float* A       = (const float*)d_in[1];
    const float* Wc      = (const float*)d_in[2];
    const float* bc      = (const float*)d_in[3];
    const float* gamma   = (const float*)d_in[4];
    const float* beta    = (const float*)d_in[5];
    const float* Wd      = (const float*)d_in[6];
    const float* bd      = (const float*)d_in[7];
    const float* gamma_d = (const float*)d_in[8];
    const float* beta_d  = (const float*)d_in[9];
    float* out = (float*)d_out;

    k0_prep<<<1, 256, 0, stream>>>(A, Wc, bc, Wd, d_ws);
    k1_main<<<2048, 512, 0, stream>>>(x, bd, d_ws);
    k2a<<<512, 256, 0, stream>>>(d_ws);
    k2b<<<1, 256, 0, stream>>>(gamma, beta, gamma_d, beta_d, bd, d_ws);
    k3_final<<<2048, 512, 0, stream>>>(x, d_ws, out);
}

// Round 5
// 155.015 us; speedup vs baseline: 3.4391x; 1.1275x over previous
//
#include <hip/hip_runtime.h>

typedef __attribute__((ext_vector_type(8))) short short8;
typedef __attribute__((ext_vector_type(4))) float floatx4;

#define N_   64
#define CIN  64
#define T_   128
#define V_   25
#define CO   128
#define MCNT 204800.0f

// ws byte offsets
#define OFF_WCF  0            // ushort[49152]  Wc A-frags [mt8][ks6][lane64][8]
#define OFF_WDF  98304        // ushort[16384]  Wd A-frags [mt8][ks2][lane64][8]
#define OFF_AF   131072       // ushort[3072]   adjacency B-frags [k3][nt2][lane64][8]
#define OFF_BC2  137216       // float[128][32] aggregated bias
#define OFF_P1   153600       // float[4][128][2048] per-block stat partials
#define OFF_SUM  4347904      // float[512]
#define OFF_STAT 4349952      // float[3][128]  s1, s2, h1+h2

__device__ __forceinline__ ushort f2bf(float f) {
    uint u = __float_as_uint(f);
    return (ushort)((u + 0x7FFFu + ((u >> 16) & 1u)) >> 16);  // RNE
}
__device__ __forceinline__ uint pack2(float a, float b) {
    return (uint)f2bf(a) | ((uint)f2bf(b) << 16);
}

// ---------------- k0: weight/adjacency fragment prep ----------------
__global__ void k0_prep(const float* __restrict__ A, const float* __restrict__ Wc,
                        const float* __restrict__ bc, const float* __restrict__ Wd,
                        void* __restrict__ wsv) {
    char* wsb = (char*)wsv;
    ushort* WCF = (ushort*)(wsb + OFF_WCF);
    ushort* WDF = (ushort*)(wsb + OFF_WDF);
    ushort* AFp = (ushort*)(wsb + OFF_AF);
    float*  BC2 = (float*)(wsb + OFF_BC2);
    int tid = threadIdx.x;
    for (int e = tid; e < 49152; e += 256) {
        int fe = e >> 3, el = e & 7;
        int l = fe & 63, q = fe >> 6;
        int mt = q / 6, ks = q % 6;
        int j = ks*32 + (l>>4)*8 + el;      // j = (k,ci) contraction index
        int c = mt*16 + (l & 15);
        int k = j >> 6, ci = j & 63;
        WCF[e] = f2bf(Wc[(k*CO + c)*CIN + ci]);
    }
    for (int e = tid; e < 16384; e += 256) {
        int fe = e >> 3, el = e & 7;
        int l = fe & 63, q = fe >> 6;
        int mt = q >> 1, ks = q & 1;
        int ci = ks*32 + (l>>4)*8 + el;
        int c = mt*16 + (l & 15);
        WDF[e] = f2bf(Wd[c*CIN + ci]);
    }
    for (int e = tid; e < 3072; e += 256) {
        int fe = e >> 3, el = e & 7;
        int l = fe & 63, q = fe >> 6;
        int k = q >> 1, nt = q & 1;
        int w = nt*16 + (l & 15);
        int v = (l>>4)*8 + el;
        AFp[e] = (v < V_ && w < V_) ? f2bf(A[(k*V_ + v)*V_ + w]) : (ushort)0;
    }
    for (int e = tid; e < 4096; e += 256) {
        int c = e >> 5, w = e & 31;
        float s = 0.f;
        if (w < V_) {
            for (int k = 0; k < 3; ++k) {
                float cs = 0.f;
                for (int v = 0; v < V_; ++v) cs += A[(k*V_ + v)*V_ + w];
                s += bc[k*CO + c] * cs;
            }
        }
        BC2[e] = s;
    }
}

// ---------------- k1: MFMA forward; stores packed (y2,res) bf16 pair into out; stats ----------------
// grid 2048; nb = blk&63 (XCD affinity), tcb = blk>>6; block 512 = 8 waves
__global__ __launch_bounds__(512, 4) void k1_main(
        const float* __restrict__ x, const float* __restrict__ bd,
        void* __restrict__ wsv, uint* __restrict__ outu) {
    char* wsb = (char*)wsv;
    const ushort* WCF = (const ushort*)(wsb + OFF_WCF);
    const ushort* WDF = (const ushort*)(wsb + OFF_WDF);
    const ushort* AF  = (const ushort*)(wsb + OFF_AF);
    const float*  BC2 = (const float*)(wsb + OFF_BC2);
    float* P1 = (float*)(wsb + OFF_P1);

    __shared__ ushort XR[8192];    // [ci64][t4][v32] bf16, 16B-slot XOR swizzle (2-bit key)
    __shared__ ushort BB[8192];    // B-frag buffer: [ks2][nt8][lane64][8]
    short8* XR8 = (short8*)XR;
    short8* BB8 = (short8*)BB;
    uint*   XRu = (uint*)XR;
    uint*   BBu = (uint*)BB;

    const int tid = threadIdx.x;
    const int l = tid & 63, wv = tid >> 6;
    const int blk = blockIdx.x;
    const int nb = blk & 63, tcb = blk >> 6;
    const long xbase = (long)nb * (CIN * T_ * V_);
    const int tg0 = tcb * 4;

    // ---- stage x -> XR ----
    #pragma unroll
    for (int i = 0; i < 8; ++i) {
        int p = tid + i * 512;
        int ci = p >> 6, rem = p & 63, t = rem >> 4, vp = rem & 15, v = vp * 2;
        float f0 = 0.f, f1 = 0.f;
        if (v < V_)     f0 = x[xbase + ci*(T_*V_) + (tg0 + t)*V_ + v];
        if (v + 1 < V_) f1 = x[xbase + ci*(T_*V_) + (tg0 + t)*V_ + v + 1];
        int idx = (ci*4 + t)*16 + 4*((v >> 3) ^ (ci & 3)) + ((v & 7) >> 1);
        XRu[idx] = (uint)f2bf(f0) | ((uint)f2bf(f1) << 16);
    }

    short8 wcf[6];
    #pragma unroll
    for (int ks = 0; ks < 6; ++ks)
        wcf[ks] = *(const short8*)(WCF + ((wv*6 + ks)*64 + l)*8);

    __syncthreads();

    // ---- main path: agg (MFMA) -> y2 GEMM (MFMA) ----
    const int t_a = wv & 3, nt_a = wv >> 2;
    short8 xf[4];
    #pragma unroll
    for (int mt = 0; mt < 4; ++mt) {
        int ci = mt*16 + (l & 15), vg = l >> 4;
        xf[mt] = XR8[(ci*4 + t_a)*4 + (vg ^ (ci & 3))];
    }
    floatx4 acc[8];
    #pragma unroll
    for (int i = 0; i < 8; ++i) acc[i] = (floatx4){0,0,0,0};

    for (int k = 0; k < 3; ++k) {
        __syncthreads();
        short8 am = *(const short8*)(AF + ((k*2 + nt_a)*64 + l)*8);
        int ntm_a = t_a*2 + nt_a;
        #pragma unroll
        for (int mt = 0; mt < 4; ++mt) {
            floatx4 agc = __builtin_amdgcn_mfma_f32_16x16x32_bf16(
                xf[mt], am, (floatx4){0,0,0,0}, 0, 0, 0);
            int kb = mt >> 1;
            #pragma unroll
            for (int rp = 0; rp < 4; rp += 2) {
                int jo = (l >> 4)*4 + rp;
                int lf = (l & 15) + 16*((mt & 1)*2 + (jo >> 3));
                int ef = jo & 7;
                BBu[(((kb*8 + ntm_a)*64 + lf)*16 + ef*2) >> 2] = pack2(agc[rp], agc[rp+1]);
            }
        }
        __syncthreads();
        #pragma unroll
        for (int kb = 0; kb < 2; ++kb)
            #pragma unroll
            for (int ntm = 0; ntm < 8; ++ntm)
                acc[ntm] = __builtin_amdgcn_mfma_f32_16x16x32_bf16(
                    wcf[k*2 + kb], BB8[(kb*8 + ntm)*64 + l], acc[ntm], 0, 0, 0);
    }

    // ---- y2: add bias, keep values in acc, accumulate stats ----
    const int cbase = wv*16 + (l >> 4)*4;
    float ys[4] = {0,0,0,0}, yss[4] = {0,0,0,0};
    #pragma unroll
    for (int ntm = 0; ntm < 8; ++ntm) {
        int n = ntm*16 + (l & 15), w = n & 31;
        bool valid = w < V_;
        #pragma unroll
        for (int r = 0; r < 4; ++r) {
            float val = acc[ntm][r] + BC2[(cbase + r)*32 + w];
            acc[ntm][r] = val;
            if (valid) { ys[r] += val; yss[r] += val*val; }
        }
    }
    #pragma unroll
    for (int m = 1; m < 16; m <<= 1)
        #pragma unroll
        for (int r = 0; r < 4; ++r) {
            ys[r]  += __shfl_xor(ys[r],  m);
            yss[r] += __shfl_xor(yss[r], m);
        }
    if ((l & 15) == 0)
        #pragma unroll
        for (int r = 0; r < 4; ++r) {
            int c = cbase + r;
            P1[(0*128 + c)*2048 + blk] = ys[r];
            P1[(1*128 + c)*2048 + blk] = yss[r];
        }

    // ---- residual: rebuild BB with x B-frags (K=ci), MFMA, pack+store, stats ----
    __syncthreads();   // all waves done reading BB from main GEMM
    #pragma unroll
    for (int i = 0; i < 2; ++i) {
        int task = tid + i*512;
        int fid = task >> 6, tl = task & 63;
        int n = (fid & 7)*16 + (tl & 15), t = n >> 5, v = n & 31;
        short8 r8;
        #pragma unroll
        for (int e = 0; e < 8; ++e) {
            int ci = (fid >> 3)*32 + (tl >> 4)*8 + e;
            r8[e] = (short)XR[(ci*4 + t)*32 + 8*((v >> 3) ^ (ci & 3)) + (v & 7)];
        }
        BB8[fid*64 + tl] = r8;
    }
    __syncthreads();

    short8 wdf[2];
    #pragma unroll
    for (int ks = 0; ks < 2; ++ks)
        wdf[ks] = *(const short8*)(WDF + ((wv*2 + ks)*64 + l)*8);
    float bdv[4];
    #pragma unroll
    for (int r = 0; r < 4; ++r) bdv[r] = bd[cbase + r];

    const long obase = (long)nb * 409600 + (long)tg0 * 25;
    float rs[4] = {0,0,0,0}, rss[4] = {0,0,0,0};
    #pragma unroll
    for (int g = 0; g < 2; ++g) {
        floatx4 racc[4];
        #pragma unroll
        for (int m = 0; m < 4; ++m) racc[m] = (floatx4){0,0,0,0};
        #pragma unroll
        for (int ks = 0; ks < 2; ++ks)
            #pragma unroll
            for (int m = 0; m < 4; ++m)
                racc[m] = __builtin_amdgcn_mfma_f32_16x16x32_bf16(
                    wdf[ks], BB8[(ks*8 + g*4 + m)*64 + l], racc[m], 0, 0, 0);
        #pragma unroll
        for (int m = 0; m < 4; ++m) {
            int ntm = g*4 + m;
            int n = ntm*16 + (l & 15), t = n >> 5, w = n & 31;
            bool valid = w < V_;
            #pragma unroll
            for (int r = 0; r < 4; ++r) {
                float rv = racc[m][r] + bdv[r];
                if (valid) {
                    rs[r] += rv; rss[r] += rv*rv;
                    outu[obase + (long)(cbase + r)*3200 + t*25 + w] = pack2(acc[ntm][r], rv);
                }
            }
        }
    }
    #pragma unroll
    for (int m = 1; m < 16; m <<= 1)
        #pragma unroll
        for (int r = 0; r < 4; ++r) {
            rs[r]  += __shfl_xor(rs[r],  m);
            rss[r] += __shfl_xor(rss[r], m);
        }
    if ((l & 15) == 0)
        #pragma unroll
        for (int r = 0; r < 4; ++r) {
            int c = cbase + r;
            P1[(2*128 + c)*2048 + blk] = rs[r];
            P1[(3*128 + c)*2048 + blk] = rss[r];
        }
}

// ---------------- k2a/k2b: deterministic stat reduction + folding ----------------
__global__ void k2a(void* __restrict__ wsv) {
    char* wsb = (char*)wsv;
    const float* P1 = (const float*)(wsb + OFF_P1);
    float* SUM = (float*)(wsb + OFF_SUM);
    __shared__ float red[256];
    int gc = blockIdx.x;
    float s = 0.f;
    for (int i = threadIdx.x; i < 2048; i += 256) s += P1[(long)gc*2048 + i];
    red[threadIdx.x] = s; __syncthreads();
    for (int st = 128; st > 0; st >>= 1) {
        if (threadIdx.x < st) red[threadIdx.x] += red[threadIdx.x + st];
        __syncthreads();
    }
    if (threadIdx.x == 0) SUM[gc] = red[0];
}

__global__ void k2b(const float* __restrict__ gamma, const float* __restrict__ beta,
                    const float* __restrict__ gamma_d, const float* __restrict__ beta_d,
                    void* __restrict__ wsv) {
    char* wsb = (char*)wsv;
    const float* SUM = (const float*)(wsb + OFF_SUM);
    float* STAT = (float*)(wsb + OFF_STAT);
    int c = threadIdx.x;
    if (c < 128) {
        float my = SUM[c] / MCNT;
        float vy = fmaxf(SUM[128 + c] / MCNT - my*my, 0.f);
        float s1 = rsqrtf(vy + 1e-5f) * gamma[c];
        float h1 = beta[c] - my * s1;
        float mr = SUM[256 + c] / MCNT;     // res stats already include bd
        float vr = fmaxf(SUM[384 + c] / MCNT - mr*mr, 0.f);
        float s2 = rsqrtf(vr + 1e-5f) * gamma_d[c];
        float h2 = beta_d[c] - mr * s2;
        STAT[c] = s1; STAT[128 + c] = s2; STAT[256 + c] = h1 + h2;
    }
}

// ---------------- k3: in-place streaming map: packed(y2,res) -> relu(y2*s1+res*s2+h) ----------------
__global__ __launch_bounds__(256) void k3_map(void* __restrict__ wsv, uint* __restrict__ outu) {
    const float* STAT = (const float*)((const char*)wsv + OFF_STAT);
    __shared__ float sS[384];
    for (int i = threadIdx.x; i < 384; i += 256) sS[i] = STAT[i];
    __syncthreads();
    const int total4 = 6553600;                 // 26214400 uints / 4
    int stride = gridDim.x * blockDim.x;
    for (int j = blockIdx.x * blockDim.x + threadIdx.x; j < total4; j += stride) {
        uint4 u = ((const uint4*)outu)[j];
        int c = (j / 800) & 127;                // c = (4j / 3200) % 128
        float s1 = sS[c], s2 = sS[128 + c], h = sS[256 + c];
        float4 o;
        o.x = fmaxf(__uint_as_float(u.x << 16) * s1 + __uint_as_float(u.x & 0xFFFF0000u) * s2 + h, 0.f);
        o.y = fmaxf(__uint_as_float(u.y << 16) * s1 + __uint_as_float(u.y & 0xFFFF0000u) * s2 + h, 0.f);
        o.z = fmaxf(__uint_as_float(u.z << 16) * s1 + __uint_as_float(u.z & 0xFFFF0000u) * s2 + h, 0.f);
        o.w = fmaxf(__uint_as_float(u.w << 16) * s1 + __uint_as_float(u.w & 0xFFFF0000u) * s2 + h, 0.f);
        ((float4*)outu)[j] = o;
    }
}

extern "C" void kernel_launch(void* const* d_in, const int* in_sizes, int n_in,
                              void* d_out, int out_size, void* d_ws, size_t ws_size,
                              hipStream_t stream) {
    const float* x       = (const float*)d_in[0];
    const float* A       = (const float*)d_in[1];
    const float* Wc      = (const float*)d_in[2];
    const float* bc      = (const float*)d_in[3];
    const float* gamma   = (const float*)d_in[4];
    const float* beta    = (const float*)d_in[5];
    const float* Wd      = (const float*)d_in[6];
    const float* bd      = (const float*)d_in[7];
    const float* gamma_d = (const float*)d_in[8];
    const float* beta_d  = (const float*)d_in[9];
    uint* outu = (uint*)d_out;

    k0_prep<<<1, 256, 0, stream>>>(A, Wc, bc, Wd, d_ws);
    k1_main<<<2048, 512, 0, stream>>>(x, bd, d_ws, outu);
    k2a<<<512, 256, 0, stream>>>(d_ws);
    k2b<<<1, 128, 0, stream>>>(gamma, beta, gamma_d, beta_d, d_ws);
    k3_map<<<2048, 256, 0, stream>>>(d_ws, outu);
}